// Round 4
// baseline (801.836 us; speedup 1.0000x reference)
//
#include <hip/hip_runtime.h>
#include <hip/hip_bf16.h>

#define NN 50000     // nodes
#define NE 600000    // edges
#define NF 11        // raw features
#define DD 128       // hidden dim
#define NB 500       // graphs
#define MA 100       // max atoms per graph
#define NLAY 5       // conv layers

// --- zero an int region ----------------------------------------------------
__global__ __launch_bounds__(256) void k_zero(int* __restrict__ p, int n) {
    int i = blockIdx.x * 256 + threadIdx.x;
    if (i < n) p[i] = 0;
}

// --- expansion: x = log(atoms+1) @ W_exp + b_exp ---------------------------
__global__ __launch_bounds__(256) void k_expand(
        const float* __restrict__ atoms,
        const float* __restrict__ W_exp,
        const float* __restrict__ b_exp,
        float* __restrict__ x) {
    int sub  = threadIdx.x >> 7;            // 2 nodes per block
    int node = blockIdx.x * 2 + sub;
    int d    = threadIdx.x & 127;
    __shared__ float la[2][NF];
    if (node < NN && d < NF)
        la[sub][d] = logf(atoms[node * NF + d] + 1.0f);
    __syncthreads();
    if (node >= NN) return;
    float acc = b_exp[d];
#pragma unroll
    for (int f = 0; f < NF; ++f)
        acc = fmaf(la[sub][f], W_exp[f * DD + d], acc);
    x[(size_t)node * DD + d] = acc;
}

// --- degree count ----------------------------------------------------------
__global__ __launch_bounds__(256) void k_count(const int* __restrict__ col,
                                               int* __restrict__ cnt) {
    int e = blockIdx.x * 256 + threadIdx.x;
    if (e < NE) atomicAdd(cnt + col[e], 1);
}

// --- dinv / self_norm ------------------------------------------------------
__global__ __launch_bounds__(256) void k_dinv(const int* __restrict__ cnt,
                                              float* __restrict__ dinv,
                                              float* __restrict__ selfn) {
    int n = blockIdx.x * 256 + threadIdx.x;
    if (n < NN) {
        float r = 1.0f / sqrtf((float)cnt[n] + 2.0f);
        dinv[n]  = r;
        selfn[n] = 2.0f * r * r;
    }
}

// --- exclusive scan of cnt -> ptr (single block, 1024 thr) -----------------
__global__ __launch_bounds__(1024) void k_scan(const int* __restrict__ cnt,
                                               int* __restrict__ ptrb) {
    __shared__ int s[1024];
    __shared__ int s_run;
    int t = threadIdx.x;
    if (t == 0) s_run = 0;
    __syncthreads();
    for (int base = 0; base < NN; base += 1024) {
        int i = base + t;
        int v = (i < NN) ? cnt[i] : 0;
        s[t] = v;
        __syncthreads();
        for (int off = 1; off < 1024; off <<= 1) {
            int tv = (t >= off) ? s[t - off] : 0;
            __syncthreads();
            s[t] += tv;
            __syncthreads();
        }
        if (i < NN) ptrb[i] = s_run + s[t] - v;
        __syncthreads();
        if (t == 1023) s_run += s[1023];
        __syncthreads();
    }
    if (t == 0) ptrb[NN] = s_run;
}

// --- scatter edges into CSR (sorted by target) -----------------------------
__global__ __launch_bounds__(256) void k_scatter(
        const int* __restrict__ conn, const int* __restrict__ ptrb,
        int* __restrict__ cursor, const float* __restrict__ dinv,
        int* __restrict__ ssrc, float* __restrict__ swt) {
    int e = blockIdx.x * 256 + threadIdx.x;
    if (e < NE) {
        int r = conn[e];
        int c = conn[NE + e];
        int p = ptrb[c] + atomicAdd(cursor + c, 1);
        ssrc[p] = r;
        swt[p]  = dinv[r] * dinv[c];
    }
}

// --- SpMM: y = P x (one wave per node, float2 per lane) --------------------
__global__ __launch_bounds__(256) void k_spmm(
        const float* __restrict__ x, const int* __restrict__ ptrb,
        const int* __restrict__ ssrc, const float* __restrict__ swt,
        const float* __restrict__ selfn, float* __restrict__ y) {
    int node = blockIdx.x * 4 + (threadIdx.x >> 6);
    if (node >= NN) return;
    int lane = threadIdx.x & 63;
    const float2* x2 = (const float2*)x;
    int p0 = ptrb[node], p1 = ptrb[node + 1];
    float sn = selfn[node];
    float2 v = x2[(size_t)node * 64 + lane];
    float a0 = v.x * sn, a1 = v.y * sn;
    for (int p = p0; p < p1; ++p) {
        int   s = ssrc[p];
        float w = swt[p];
        float2 u = x2[(size_t)s * 64 + lane];
        a0 = fmaf(u.x, w, a0);
        a1 = fmaf(u.y, w, a1);
    }
    float2 o; o.x = a0; o.y = a1;
    ((float2*)y)[(size_t)node * 64 + lane] = o;
}

// --- GEMM + bias + relu: x = relu(y @ W + b) -------------------------------
// 16 nodes/block, 256 threads. LDS: W half (32KB) + y tile (8KB) = 40KB.
__global__ __launch_bounds__(256) void k_gemm(
        const float* __restrict__ y, const float* __restrict__ W,
        const float* __restrict__ bias, float* __restrict__ xo) {
    __shared__ float Wl[64 * DD];   // 32 KB (one K-half of W)
    __shared__ float yt[16 * DD];   // 8 KB
    int tid = threadIdx.x;
    int nodebase = blockIdx.x * 16;
    const float4* ysrc = (const float4*)(y + (size_t)nodebase * DD);
    for (int i = tid; i < 16 * DD / 4; i += 256)
        ((float4*)yt)[i] = ysrc[i];

    int dg = tid & 31;  int d0 = dg * 4;
    int np = tid >> 5;  int n0 = np * 2, n1 = n0 + 1;
    float a0x = 0, a0y = 0, a0z = 0, a0w = 0;
    float a1x = 0, a1y = 0, a1z = 0, a1w = 0;

#pragma unroll
    for (int half = 0; half < 2; ++half) {
        __syncthreads();
        const float4* Wv = (const float4*)(W + (size_t)half * 64 * DD);
        for (int i = tid; i < 64 * DD / 4; i += 256)
            ((float4*)Wl)[i] = Wv[i];
        __syncthreads();
        int kb = half * 64;
#pragma unroll 4
        for (int k = 0; k < 64; ++k) {
            float4 wv = *(const float4*)&Wl[k * DD + d0];
            float ya = yt[n0 * DD + kb + k];
            float yb = yt[n1 * DD + kb + k];
            a0x = fmaf(wv.x, ya, a0x); a0y = fmaf(wv.y, ya, a0y);
            a0z = fmaf(wv.z, ya, a0z); a0w = fmaf(wv.w, ya, a0w);
            a1x = fmaf(wv.x, yb, a1x); a1y = fmaf(wv.y, yb, a1y);
            a1z = fmaf(wv.z, yb, a1z); a1w = fmaf(wv.w, yb, a1w);
        }
    }
    float4 bv = ((const float4*)bias)[dg];
    float4 o0, o1;
    o0.x = fmaxf(a0x + bv.x, 0.0f); o0.y = fmaxf(a0y + bv.y, 0.0f);
    o0.z = fmaxf(a0z + bv.z, 0.0f); o0.w = fmaxf(a0w + bv.w, 0.0f);
    o1.x = fmaxf(a1x + bv.x, 0.0f); o1.y = fmaxf(a1y + bv.y, 0.0f);
    o1.z = fmaxf(a1z + bv.z, 0.0f); o1.w = fmaxf(a1w + bv.w, 0.0f);
    *(float4*)&xo[(size_t)(nodebase + n0) * DD + d0] = o0;
    *(float4*)&xo[(size_t)(nodebase + n1) * DD + d0] = o1;
}

// --- per-graph counts ------------------------------------------------------
__global__ __launch_bounds__(256) void k_gcount(const int* __restrict__ batch,
                                                int* __restrict__ gcnt) {
    int n = blockIdx.x * 256 + threadIdx.x;
    if (n < NN) atomicAdd(gcnt + batch[n], 1);
}

__global__ __launch_bounds__(512) void k_gscan(const int* __restrict__ gcnt,
                                               int* __restrict__ gptr) {
    __shared__ int s[512];
    int t = threadIdx.x;
    int v = (t < NB) ? gcnt[t] : 0;
    s[t] = v;
    __syncthreads();
    for (int off = 1; off < 512; off <<= 1) {
        int tv = (t >= off) ? s[t - off] : 0;
        __syncthreads();
        s[t] += tv;
        __syncthreads();
    }
    if (t < NB) gptr[t] = s[t] - v;
}

// --- to_dense_batch output: dense f32 [B*MA*DD] then mask f32 [B*MA] -------
// idx = batch*MA + (node - gptr[batch]) is bijective over [0, NN) here,
// so every dense element and every mask element is written each call.
__global__ __launch_bounds__(256) void k_output(
        const float* __restrict__ x, const int* __restrict__ batch,
        const int* __restrict__ gptr, float* __restrict__ out) {
    int sub  = threadIdx.x >> 7;
    int node = blockIdx.x * 2 + sub;
    int d    = threadIdx.x & 127;
    if (node >= NN) return;
    int b   = batch[node];
    int pos = node - gptr[b];
    int idx = b * MA + pos;
    out[(size_t)idx * DD + d] = x[(size_t)node * DD + d];
    if (d == 0)
        out[(size_t)NB * MA * DD + idx] = 1.0f;   // mask True -> 1.0f
}

extern "C" void kernel_launch(void* const* d_in, const int* in_sizes, int n_in,
                              void* d_out, int out_size, void* d_ws, size_t ws_size,
                              hipStream_t stream) {
    const float* atoms = (const float*)d_in[0];
    const int*   conn  = (const int*)d_in[1];
    const int*   batch = (const int*)d_in[2];
    const float* W_exp = (const float*)d_in[3];
    const float* b_exp = (const float*)d_in[4];
    const float* Ws    = (const float*)d_in[5];
    const float* bs    = (const float*)d_in[6];
    float* out = (float*)d_out;   // reference output dtype is float32

    char* ws = (char*)d_ws;
    size_t off = 0;
    auto nextbuf = [&](size_t bytes) {
        void* p = ws + off;
        off = (off + bytes + 255) & ~(size_t)255;
        return p;
    };
    float* xbuf  = (float*)nextbuf((size_t)NN * DD * 4);
    float* ybuf  = (float*)nextbuf((size_t)NN * DD * 4);
    int*   izero = (int*)  nextbuf((size_t)(2 * NN + NB) * 4);  // cnt|cursor|gcnt
    int*   cnt    = izero;
    int*   cursor = izero + NN;
    int*   gcnt   = izero + 2 * NN;
    int*   ptrb  = (int*)  nextbuf((size_t)(NN + 1) * 4);
    float* dinv  = (float*)nextbuf((size_t)NN * 4);
    float* selfn = (float*)nextbuf((size_t)NN * 4);
    int*   ssrc  = (int*)  nextbuf((size_t)NE * 4);
    float* swt   = (float*)nextbuf((size_t)NE * 4);
    int*   gptr  = (int*)  nextbuf((size_t)NB * 4);
    (void)ws_size; (void)n_in; (void)in_sizes; (void)out_size;

    const int NZ = 2 * NN + NB;
    k_zero   <<<(NZ + 255) / 256,    256, 0, stream>>>(izero, NZ);
    k_expand <<<NN / 2,              256, 0, stream>>>(atoms, W_exp, b_exp, xbuf);
    k_count  <<<(NE + 255) / 256,    256, 0, stream>>>(conn + NE, cnt);
    k_dinv   <<<(NN + 255) / 256,    256, 0, stream>>>(cnt, dinv, selfn);
    k_scan   <<<1,                  1024, 0, stream>>>(cnt, ptrb);
    k_scatter<<<(NE + 255) / 256,    256, 0, stream>>>(conn, ptrb, cursor, dinv, ssrc, swt);
    k_gcount <<<(NN + 255) / 256,    256, 0, stream>>>(batch, gcnt);
    k_gscan  <<<1,                   512, 0, stream>>>(gcnt, gptr);

    for (int l = 0; l < NLAY; ++l) {
        k_spmm<<<NN / 4,  256, 0, stream>>>(xbuf, ptrb, ssrc, swt, selfn, ybuf);
        k_gemm<<<NN / 16, 256, 0, stream>>>(ybuf, Ws + (size_t)l * DD * DD,
                                            bs + (size_t)l * DD, xbuf);
    }
    k_output<<<NN / 2, 256, 0, stream>>>(xbuf, batch, gptr, out);
}